// Round 7
// baseline (45.028 us; speedup 1.0000x reference)
//
#include <hip/hip_runtime.h>
#include <math.h>

// Loss: per row i of output/target (B x 3 f32):
//   ang = 2*pi*(x-0.5); v = euler_to_vec(ang); per = 1 - |cross(vo,vt)| + dot(vo,vt)
//   result = sum over B.
//
// R6 design notes:
// - v_sin/v_cos take REVOLUTIONS: sin(2*pi*(x-0.5)) == __builtin_amdgcn_sinf(x-0.5f).
// - R1/R2/R5: register-staged structures all plateau at ~5.8 TB/s read, but the
//   harness's fill kernel writes at 7.1 TB/s -> fabric has headroom. Suspected
//   gap: VGPR-roundtrip staging bubbles (vmcnt(0) at ds_write + barrier).
// - R6: global_load_lds DMA staging, width=12 = one 12B row per lane, linear
//   LDS dest (wave-uniform base + lane*12 — matches the HW requirement).
//   Double-buffered 2x24KB; __syncthreads' vmcnt(0) drain lands AFTER compute,
//   so each tile's DMA hides under the current tile's compute. LDS row reads
//   at 12B stride -> banks 3l%32, 2-way aliasing = free.
// - R3 lesson: no ordered agent-scope atomics. R4 lesson: no memset nodes.

#define NBLOCKS 2048
#define NTHREADS 512
#define TILE_ROWS 1024  // rows per buffer; 12 KB per input per buffer

__device__ __forceinline__ float sample_loss(float a, float b, float c,
                                             float d, float e, float f) {
  float oy = a - 0.5f, op = b - 0.5f, orr = c - 0.5f;
  float ty = d - 0.5f, tp = e - 0.5f, trr = f - 0.5f;

  float cy = __builtin_amdgcn_cosf(oy), sy = __builtin_amdgcn_sinf(oy);
  float cp = __builtin_amdgcn_cosf(op), sp = __builtin_amdgcn_sinf(op);
  float cr = __builtin_amdgcn_cosf(orr), sr = __builtin_amdgcn_sinf(orr);

  float vox = cy * sp * cr + sy * sr;
  float voy = sy * sp * cr - cy * sr;
  float voz = cp * cr;

  float cy2 = __builtin_amdgcn_cosf(ty), sy2 = __builtin_amdgcn_sinf(ty);
  float cp2 = __builtin_amdgcn_cosf(tp), sp2 = __builtin_amdgcn_sinf(tp);
  float cr2 = __builtin_amdgcn_cosf(trr), sr2 = __builtin_amdgcn_sinf(trr);

  float vtx = cy2 * sp2 * cr2 + sy2 * sr2;
  float vty = sy2 * sp2 * cr2 - cy2 * sr2;
  float vtz = cp2 * cr2;

  float crx = voy * vtz - voz * vty;
  float cry = voz * vtx - vox * vtz;
  float crz = vox * vty - voy * vtx;

  float cn = sqrtf(crx * crx + cry * cry + crz * crz);
  float dot = vox * vtx + voy * vty + voz * vtz;
  return 1.0f - cn + dot;
}

template <int NT>
__device__ __forceinline__ float block_reduce(float acc) {
  #pragma unroll
  for (int off = 32; off > 0; off >>= 1) acc += __shfl_down(acc, off, 64);
  __shared__ float ws[NT / 64];
  int lane = threadIdx.x & 63;
  int wave = threadIdx.x >> 6;
  if (lane == 0) ws[wave] = acc;
  __syncthreads();
  float tot = 0.0f;
  if (threadIdx.x == 0) {
    #pragma unroll
    for (int w = 0; w < NT / 64; ++w) tot += ws[w];
  }
  return tot;  // valid in thread 0 only
}

__global__ __launch_bounds__(NTHREADS) void loss_partial_kernel(
    const float* __restrict__ out, const float* __restrict__ tgt,
    float* __restrict__ partial, int B) {
  // [2] = double buffer; each buffer holds TILE_ROWS rows (12 B each)
  __shared__ float bufO[2][TILE_ROWS * 3];
  __shared__ float bufT[2][TILE_ROWS * 3];

  const int t = threadIdx.x;
  const int w = t >> 6;   // wave id (0..7)
  const int l = t & 63;   // lane
  const int ntiles = B / TILE_ROWS;

  float acc = 0.0f;
  int tile = blockIdx.x;
  int cur = 0;

  // DMA one tile (both inputs) into buffer `bi`. Per wave-instr: 64 lanes x
  // 12 B = 64 consecutive rows, LDS dest linear at wave-uniform base.
  auto stage = [&](int bi, int tl) {
    const long rowbase = (long)tl * TILE_ROWS;
    #pragma unroll
    for (int k = 0; k < 2; ++k) {
      const int lrow = k * (NTHREADS) + w * 64;  // wave-uniform row offset
      const float* gO = out + (rowbase + lrow + l) * 3;
      const float* gT = tgt + (rowbase + lrow + l) * 3;
      float* dO = &bufO[bi][lrow * 3];
      float* dT = &bufT[bi][lrow * 3];
      __builtin_amdgcn_global_load_lds(
          (const __attribute__((address_space(1))) void*)gO,
          (__attribute__((address_space(3))) void*)dO, 12, 0, 0);
      __builtin_amdgcn_global_load_lds(
          (const __attribute__((address_space(1))) void*)gT,
          (__attribute__((address_space(3))) void*)dT, 12, 0, 0);
    }
  };

  if (tile < ntiles) stage(0, tile);
  __syncthreads();  // drain prologue DMA (vmcnt(0)) + barrier

  while (tile < ntiles) {
    const int next = tile + gridDim.x;
    if (next < ntiles) stage(cur ^ 1, next);  // DMA overlaps compute below

    #pragma unroll
    for (int k = 0; k < 2; ++k) {
      const int r = t + k * NTHREADS;  // rows t and t+512
      acc += sample_loss(bufO[cur][3 * r], bufO[cur][3 * r + 1],
                         bufO[cur][3 * r + 2], bufT[cur][3 * r],
                         bufT[cur][3 * r + 1], bufT[cur][3 * r + 2]);
    }
    __syncthreads();  // vmcnt(0): next-tile DMA done; barrier: reads done
    cur ^= 1;
    tile = next;
  }

  // tail rows (B not divisible by TILE_ROWS) — scalar, distributed
  const int done = ntiles * TILE_ROWS;
  for (int r = done + blockIdx.x * NTHREADS + t; r < B;
       r += gridDim.x * NTHREADS) {
    acc += sample_loss(out[3 * r], out[3 * r + 1], out[3 * r + 2],
                       tgt[3 * r], tgt[3 * r + 1], tgt[3 * r + 2]);
  }

  float tot = block_reduce<NTHREADS>(acc);
  if (t == 0) partial[blockIdx.x] = tot;
}

// One wave, pure shuffle reduce — no LDS, no __syncthreads.
__global__ __launch_bounds__(64) void final_reduce_kernel(
    const float* __restrict__ partial, int n, float* __restrict__ out) {
  float acc = 0.0f;
  for (int i = threadIdx.x; i < n; i += 64) acc += partial[i];
  #pragma unroll
  for (int off = 32; off > 0; off >>= 1) acc += __shfl_down(acc, off, 64);
  if (threadIdx.x == 0) out[0] = acc;
}

extern "C" void kernel_launch(void* const* d_in, const int* in_sizes, int n_in,
                              void* d_out, int out_size, void* d_ws, size_t ws_size,
                              hipStream_t stream) {
  const float* d_output = (const float*)d_in[0];
  const float* d_target = (const float*)d_in[1];
  float* partial = (float*)d_ws;  // NBLOCKS floats of scratch
  float* out = (float*)d_out;     // 1 float
  const int B = in_sizes[0] / 3;

  loss_partial_kernel<<<NBLOCKS, NTHREADS, 0, stream>>>(d_output, d_target,
                                                        partial, B);
  final_reduce_kernel<<<1, 64, 0, stream>>>(partial, NBLOCKS, out);
}

// Round 8
// 40.430 us; speedup vs baseline: 1.1137x; 1.1137x over previous
//
#include <hip/hip_runtime.h>
#include <math.h>

// Loss: per row i of output/target (B x 3 f32):
//   ang = 2*pi*(x-0.5); v = euler_to_vec(ang); per = 1 - |cross(vo,vt)| + dot(vo,vt)
//   result = sum over B.
//
// R7 design notes:
// - v_sin/v_cos take REVOLUTIONS: sin(2*pi*(x-0.5)) == __builtin_amdgcn_sinf(x-0.5f).
// - Bench-vs-profile comparison shows rocprof inflates this kernel ~2x; trust
//   bench dur_us. Best so far: R2 LDS-staged structure, 38.0us total
//   (~5.8 TB/s read; copy ceiling 6.29, fill kernel writes at 7.1).
// - R6 lesson: global_load_lds width=12 is both slower (LDS-occupancy) and
//   NOT bit-reliable (absmax 32768 vs 0) — only 4B/16B widths are HW-verified.
// - R3 lesson: no ordered agent-scope atomics. R4 lesson: no memset/SDMA nodes.
// - R7: same structure, dense float4 (dwordx4) staging — half the global-load
//   instructions per byte vs float2. TILE_ROWS=2048 divides B exactly (no tail).

#define NBLOCKS 1024
#define NTHREADS 512
#define TILE_ROWS 2048                  // 24 KB per input per tile
#define TILE_F4 (TILE_ROWS * 3 / 4)     // 1536 float4 per input

__device__ __forceinline__ float sample_loss(float a, float b, float c,
                                             float d, float e, float f) {
  float oy = a - 0.5f, op = b - 0.5f, orr = c - 0.5f;
  float ty = d - 0.5f, tp = e - 0.5f, trr = f - 0.5f;

  float cy = __builtin_amdgcn_cosf(oy), sy = __builtin_amdgcn_sinf(oy);
  float cp = __builtin_amdgcn_cosf(op), sp = __builtin_amdgcn_sinf(op);
  float cr = __builtin_amdgcn_cosf(orr), sr = __builtin_amdgcn_sinf(orr);

  float vox = cy * sp * cr + sy * sr;
  float voy = sy * sp * cr - cy * sr;
  float voz = cp * cr;

  float cy2 = __builtin_amdgcn_cosf(ty), sy2 = __builtin_amdgcn_sinf(ty);
  float cp2 = __builtin_amdgcn_cosf(tp), sp2 = __builtin_amdgcn_sinf(tp);
  float cr2 = __builtin_amdgcn_cosf(trr), sr2 = __builtin_amdgcn_sinf(trr);

  float vtx = cy2 * sp2 * cr2 + sy2 * sr2;
  float vty = sy2 * sp2 * cr2 - cy2 * sr2;
  float vtz = cp2 * cr2;

  float crx = voy * vtz - voz * vty;
  float cry = voz * vtx - vox * vtz;
  float crz = vox * vty - voy * vtx;

  float cn = sqrtf(crx * crx + cry * cry + crz * crz);
  float dot = vox * vtx + voy * vty + voz * vtz;
  return 1.0f - cn + dot;
}

template <int NT>
__device__ __forceinline__ float block_reduce(float acc) {
  #pragma unroll
  for (int off = 32; off > 0; off >>= 1) acc += __shfl_down(acc, off, 64);
  __shared__ float ws[NT / 64];
  int lane = threadIdx.x & 63;
  int wave = threadIdx.x >> 6;
  if (lane == 0) ws[wave] = acc;
  __syncthreads();
  float tot = 0.0f;
  if (threadIdx.x == 0) {
    #pragma unroll
    for (int w = 0; w < NT / 64; ++w) tot += ws[w];
  }
  return tot;  // valid in thread 0 only
}

__global__ __launch_bounds__(NTHREADS) void loss_partial_kernel(
    const float* __restrict__ out, const float* __restrict__ tgt,
    float* __restrict__ partial, int B) {
  __shared__ float4 ldsO4[TILE_F4];   // 24 KB
  __shared__ float4 ldsT4[TILE_F4];   // 24 KB
  const float* ldsO = (const float*)ldsO4;
  const float* ldsT = (const float*)ldsT4;

  const float4* __restrict__ o4 = (const float4*)out;
  const float4* __restrict__ t4 = (const float4*)tgt;

  const int t = threadIdx.x;
  const int ntiles = B / TILE_ROWS;

  float acc = 0.0f;

  int tile = blockIdx.x;
  float4 a0, a1, a2, b0, b1, b2;
  if (tile < ntiles) {
    const int g = tile * TILE_F4 + t;
    a0 = o4[g]; a1 = o4[g + NTHREADS]; a2 = o4[g + 2 * NTHREADS];
    b0 = t4[g]; b1 = t4[g + NTHREADS]; b2 = t4[g + 2 * NTHREADS];
  }

  while (tile < ntiles) {
    // dense float4 LDS writes (ds_write_b128, conflict-free)
    ldsO4[t] = a0; ldsO4[t + NTHREADS] = a1; ldsO4[t + 2 * NTHREADS] = a2;
    ldsT4[t] = b0; ldsT4[t + NTHREADS] = b1; ldsT4[t + 2 * NTHREADS] = b2;
    __syncthreads();

    // prefetch NEXT tile into registers; latency hides under compute below
    const int next = tile + gridDim.x;
    if (next < ntiles) {
      const int g = next * TILE_F4 + t;
      a0 = o4[g]; a1 = o4[g + NTHREADS]; a2 = o4[g + 2 * NTHREADS];
      b0 = t4[g]; b1 = t4[g + NTHREADS]; b2 = t4[g + 2 * NTHREADS];
    }

    // compute 4 rows/thread from LDS (12B rows: banks 3t%32 -> 2-way = free)
    #pragma unroll
    for (int k = 0; k < TILE_ROWS / NTHREADS; ++k) {
      const int r = t + k * NTHREADS;
      acc += sample_loss(ldsO[3 * r], ldsO[3 * r + 1], ldsO[3 * r + 2],
                         ldsT[3 * r], ldsT[3 * r + 1], ldsT[3 * r + 2]);
    }
    __syncthreads();
    tile = next;
  }

  // tail rows (empty for B = 8388608; kept for generality)
  const int done = ntiles * TILE_ROWS;
  for (int r = done + blockIdx.x * NTHREADS + t; r < B;
       r += gridDim.x * NTHREADS) {
    acc += sample_loss(out[3 * r], out[3 * r + 1], out[3 * r + 2],
                       tgt[3 * r], tgt[3 * r + 1], tgt[3 * r + 2]);
  }

  float tot = block_reduce<NTHREADS>(acc);
  if (t == 0) partial[blockIdx.x] = tot;
}

__global__ __launch_bounds__(256) void final_reduce_kernel(
    const float* __restrict__ partial, int n, float* __restrict__ out) {
  float acc = 0.0f;
  for (int i = threadIdx.x; i < n; i += 256) acc += partial[i];
  float tot = block_reduce<256>(acc);
  if (threadIdx.x == 0) out[0] = tot;
}

extern "C" void kernel_launch(void* const* d_in, const int* in_sizes, int n_in,
                              void* d_out, int out_size, void* d_ws, size_t ws_size,
                              hipStream_t stream) {
  const float* d_output = (const float*)d_in[0];
  const float* d_target = (const float*)d_in[1];
  float* partial = (float*)d_ws;  // NBLOCKS floats of scratch
  float* out = (float*)d_out;     // 1 float
  const int B = in_sizes[0] / 3;

  loss_partial_kernel<<<NBLOCKS, NTHREADS, 0, stream>>>(d_output, d_target,
                                                        partial, B);
  final_reduce_kernel<<<1, 256, 0, stream>>>(partial, NBLOCKS, out);
}

// Round 9
// 38.520 us; speedup vs baseline: 1.1689x; 1.0496x over previous
//
#include <hip/hip_runtime.h>
#include <math.h>

// Loss: per row i of output/target (B x 3 f32):
//   ang = 2*pi*(x-0.5); v = euler_to_vec(ang); per = 1 - |cross(vo,vt)| + dot(vo,vt)
//   result = sum over B.
//
// FINAL (R8 = R2 verbatim, measured best 38.0us):
// - v_sin/v_cos take REVOLUTIONS: sin(2*pi*(x-0.5)) == __builtin_amdgcn_sinf(x-0.5f).
// - Roofline: 201MB read-once at the measured ~5.8 TB/s read-path ceiling
//   (four independent structures plateau there: R1 reg-direct 39.7, R2 LDS
//   float2 38.0, R5 +nt 38.6, R7 LDS float4 40.4) + ~3us two-dispatch
//   finalization.
// - Rejected by measurement: ordered agent-scope atomics (R3: wbl2/inv cache
//   flush storm, +55us), hipMemsetAsync graph node (R4: SDMA semaphore, +4us),
//   global_load_lds width=12 (R6: slower + absmax 32768 — not bit-reliable),
//   float4 staging (R7: LDS occupancy), NT loads (R5: null).

#define NBLOCKS 1024
#define NTHREADS 512
#define TILE_ROWS 1024                 // rows per block-iteration
#define TILE_F2 (TILE_ROWS * 3 / 2)    // 1536 float2 per input = 12 KB

__device__ __forceinline__ float sample_loss(float a, float b, float c,
                                             float d, float e, float f) {
  float oy = a - 0.5f, op = b - 0.5f, orr = c - 0.5f;
  float ty = d - 0.5f, tp = e - 0.5f, trr = f - 0.5f;

  float cy = __builtin_amdgcn_cosf(oy), sy = __builtin_amdgcn_sinf(oy);
  float cp = __builtin_amdgcn_cosf(op), sp = __builtin_amdgcn_sinf(op);
  float cr = __builtin_amdgcn_cosf(orr), sr = __builtin_amdgcn_sinf(orr);

  float vox = cy * sp * cr + sy * sr;
  float voy = sy * sp * cr - cy * sr;
  float voz = cp * cr;

  float cy2 = __builtin_amdgcn_cosf(ty), sy2 = __builtin_amdgcn_sinf(ty);
  float cp2 = __builtin_amdgcn_cosf(tp), sp2 = __builtin_amdgcn_sinf(tp);
  float cr2 = __builtin_amdgcn_cosf(trr), sr2 = __builtin_amdgcn_sinf(trr);

  float vtx = cy2 * sp2 * cr2 + sy2 * sr2;
  float vty = sy2 * sp2 * cr2 - cy2 * sr2;
  float vtz = cp2 * cr2;

  float crx = voy * vtz - voz * vty;
  float cry = voz * vtx - vox * vtz;
  float crz = vox * vty - voy * vtx;

  float cn = sqrtf(crx * crx + cry * cry + crz * crz);
  float dot = vox * vtx + voy * vty + voz * vtz;
  return 1.0f - cn + dot;
}

template <int NT>
__device__ __forceinline__ float block_reduce(float acc) {
  #pragma unroll
  for (int off = 32; off > 0; off >>= 1) acc += __shfl_down(acc, off, 64);
  __shared__ float ws[NT / 64];
  int lane = threadIdx.x & 63;
  int wave = threadIdx.x >> 6;
  if (lane == 0) ws[wave] = acc;
  __syncthreads();
  float tot = 0.0f;
  if (threadIdx.x == 0) {
    #pragma unroll
    for (int w = 0; w < NT / 64; ++w) tot += ws[w];
  }
  return tot;  // valid in thread 0 only
}

__global__ __launch_bounds__(NTHREADS) void loss_partial_kernel(
    const float* __restrict__ out, const float* __restrict__ tgt,
    float* __restrict__ partial, int B) {
  __shared__ float2 ldsO2[TILE_F2];
  __shared__ float2 ldsT2[TILE_F2];
  const float* ldsO = (const float*)ldsO2;
  const float* ldsT = (const float*)ldsT2;

  const float2* __restrict__ o2 = (const float2*)out;
  const float2* __restrict__ t2 = (const float2*)tgt;

  const int t = threadIdx.x;
  const int ntiles = B / TILE_ROWS;

  float acc = 0.0f;

  int tile = blockIdx.x;
  float2 a0, a1, a2, b0, b1, b2;
  if (tile < ntiles) {
    const int g = tile * TILE_F2 + t;
    a0 = o2[g]; a1 = o2[g + NTHREADS]; a2 = o2[g + 2 * NTHREADS];
    b0 = t2[g]; b1 = t2[g + NTHREADS]; b2 = t2[g + 2 * NTHREADS];
  }

  while (tile < ntiles) {
    // write staged tile to LDS (dense float2, conflict-free)
    ldsO2[t] = a0; ldsO2[t + NTHREADS] = a1; ldsO2[t + 2 * NTHREADS] = a2;
    ldsT2[t] = b0; ldsT2[t + NTHREADS] = b1; ldsT2[t + 2 * NTHREADS] = b2;
    __syncthreads();

    // issue NEXT tile's global loads now; latency hides under compute.
    const int next = tile + gridDim.x;
    if (next < ntiles) {
      const int g = next * TILE_F2 + t;
      a0 = o2[g]; a1 = o2[g + NTHREADS]; a2 = o2[g + 2 * NTHREADS];
      b0 = t2[g]; b1 = t2[g + NTHREADS]; b2 = t2[g + 2 * NTHREADS];
    }

    // compute this tile from LDS: rows t + k*NTHREADS (12B rows: 2-way = free)
    #pragma unroll
    for (int k = 0; k < TILE_ROWS / NTHREADS; ++k) {
      const int r = t + k * NTHREADS;
      acc += sample_loss(ldsO[3 * r], ldsO[3 * r + 1], ldsO[3 * r + 2],
                         ldsT[3 * r], ldsT[3 * r + 1], ldsT[3 * r + 2]);
    }
    __syncthreads();
    tile = next;
  }

  // tail rows (B not divisible by TILE_ROWS) — scalar, distributed
  const int done = ntiles * TILE_ROWS;
  for (int r = done + blockIdx.x * NTHREADS + t; r < B;
       r += gridDim.x * NTHREADS) {
    acc += sample_loss(out[3 * r], out[3 * r + 1], out[3 * r + 2],
                       tgt[3 * r], tgt[3 * r + 1], tgt[3 * r + 2]);
  }

  float tot = block_reduce<NTHREADS>(acc);
  if (t == 0) partial[blockIdx.x] = tot;
}

__global__ __launch_bounds__(256) void final_reduce_kernel(
    const float* __restrict__ partial, int n, float* __restrict__ out) {
  float acc = 0.0f;
  for (int i = threadIdx.x; i < n; i += 256) acc += partial[i];
  float tot = block_reduce<256>(acc);
  if (threadIdx.x == 0) out[0] = tot;
}

extern "C" void kernel_launch(void* const* d_in, const int* in_sizes, int n_in,
                              void* d_out, int out_size, void* d_ws, size_t ws_size,
                              hipStream_t stream) {
  const float* d_output = (const float*)d_in[0];
  const float* d_target = (const float*)d_in[1];
  float* partial = (float*)d_ws;  // NBLOCKS floats of scratch
  float* out = (float*)d_out;     // 1 float
  const int B = in_sizes[0] / 3;

  loss_partial_kernel<<<NBLOCKS, NTHREADS, 0, stream>>>(d_output, d_target,
                                                        partial, B);
  final_reduce_kernel<<<1, 256, 0, stream>>>(partial, NBLOCKS, out);
}